// Round 6
// baseline (95.777 us; speedup 1.0000x reference)
//
#include <hip/hip_runtime.h>
#include <math.h>

// Base = R15 (82.1us, absmax 0.0; best structure so far). R17 = DIAGNOSTIC:
// identical R15 schedule wrapped in REP=2 -- each block runs its 4 images
// twice (idempotent: same inputs -> bitwise same outputs, rewritten). This
// lifts the ringnn dispatch to ~46-50us, ABOVE the 41-43us fill cutoff, so
// it finally appears in the top-5 rocprof rows with real counters
// (VALUBusy/Occupancy/bank-conflict/FETCH) for the R15 structure. dur_us
// prediction: ~59 (fixed harness overhead) + 2x~23 (ringnn) = 100-108.
// Rep-boundary hazards: rep N+1 phase1 writes sc1 -- its last readers
// (rep N second phase2) finished before rep N's post-P2 barrier; phase3
// reads sc2 only (disjoint). No extra barriers needed; trig2 staged once.
//
// d_ws trig layout (float2 = {cos,sin}):
//   [0,2880)    fft:   [n*288 + k]            (transposed ff_w trig)
//   [2880,3400) trig2: [ocp*130 + e*2 + (oc&1)], e = ch*16+ki*4+kj (pad 130)
//   [3400,3416) trig1: [oc*4 + e], e = a*2+c
#define FFT_OFF 0
#define W2_OFF 2880
#define W1_OFF 3400
#define REP 2   // DIAGNOSTIC: 2 for this round; revert to 1 after reading counters

__global__ void precompute_trig(const float* __restrict__ w1,
                                const float* __restrict__ w2,
                                const float* __restrict__ ff,
                                float2* __restrict__ ws) {
    int idx = blockIdx.x * blockDim.x + threadIdx.x;
    if (idx < 2880) {
        int k = idx / 10, n = idx % 10;
        float s, c; sincosf(ff[idx], &s, &c);
        ws[FFT_OFF + n * 288 + k] = make_float2(c, s);
    } else if (idx < 3392) {
        int i = idx - 2880;                  // i = oc*64 + e
        int oc = i >> 6, e = i & 63;
        float s, c; sincosf(w2[i], &s, &c);
        ws[W2_OFF + (oc >> 1) * 130 + e * 2 + (oc & 1)] = make_float2(c, s);
    } else if (idx < 3408) {
        int i = idx - 3392;
        float s, c; sincosf(w1[i], &s, &c);
        ws[W1_OFF + i] = make_float2(c, s);
    }
}

// One conv1 output position: 4 sincos + 4 oc x (16 fma + rsqrt).
// Bitwise identical to R11's per-position phase-1 body.
__device__ __forceinline__ void conv1_pos(float2 r0, float2 r1,
                                          const float2* __restrict__ w1t,
                                          float2* __restrict__ sc1,
                                          int pi, int pj) {
    float sx[4], cx[4];
    __sincosf(r0.x, &sx[0], &cx[0]);
    __sincosf(r0.y, &sx[1], &cx[1]);
    __sincosf(r1.x, &sx[2], &cx[2]);
    __sincosf(r1.y, &sx[3], &cx[3]);
    #pragma unroll
    for (int oc = 0; oc < 4; oc++) {
        float4 wa = *(const float4*)(w1t + oc * 4);      // taps e0,e1 (uniform)
        float4 wb = *(const float4*)(w1t + oc * 4 + 2);  // taps e2,e3 (uniform)
        float Y = 0.f, X = 0.f;
        Y = fmaf(sx[0], wa.x, fmaf(-cx[0], wa.y, Y));
        X = fmaf(cx[0], wa.x, fmaf( sx[0], wa.y, X));
        Y = fmaf(sx[1], wa.z, fmaf(-cx[1], wa.w, Y));
        X = fmaf(cx[1], wa.z, fmaf( sx[1], wa.w, X));
        Y = fmaf(sx[2], wb.x, fmaf(-cx[2], wb.y, Y));
        X = fmaf(cx[2], wb.x, fmaf( sx[2], wb.y, X));
        Y = fmaf(sx[3], wb.z, fmaf(-cx[3], wb.w, Y));
        X = fmaf(cx[3], wb.z, fmaf( sx[3], wb.w, X));
        float inv = rsqrtf(fmaxf(fmaf(X, X, Y * Y), 1e-30f));
        sc1[oc * 252 + pi * 18 + pj] = make_float2(Y * inv, X * inv);
    }
}

// 256 threads = 4 waves, 4 images/block (2 pairs), grid B/4 = 1024.
__global__ __launch_bounds__(256, 4) void ringnn_kernel(
    const float* __restrict__ x,
    const float2* __restrict__ ws,
    float* __restrict__ out)
{
    __shared__ __align__(16) float2 trig2[520];
    __shared__ __align__(16) float2 sc1[2 * 1008]; // img*1008 + ch*252 + row*18 + col
    __shared__ __align__(16) float2 sc2[2 * 288];  // img*288 + p*8 + oc
    const int tid = threadIdx.x;
    const float2* __restrict__ fft = ws + FFT_OFF;
    const float2* __restrict__ w1t = ws + W1_OFF;
    const size_t imgBase = (size_t)blockIdx.x * 4;

    // ---- per-thread position maps (constant across pairs) ----
    const int im0 = (tid >= 196) ? 1 : 0;
    const int p0  = tid - im0 * 196;
    const int pi0 = p0 / 14, pj0 = p0 % 14;
    const int pr1 = tid + 60;                   // img1 pos for round 1 (tid<136)
    const int pi1 = pr1 / 14, pj1 = pr1 % 14;

    float2 a0, a1, b0 = make_float2(0.f, 0.f), b1 = make_float2(0.f, 0.f);

    auto loadPair = [&](size_t pairImg) {
        const float* xb0 = x + (pairImg + im0) * 784;
        a0 = *(const float2*)(xb0 + (2 * pi0) * 28 + 2 * pj0);
        a1 = *(const float2*)(xb0 + (2 * pi0 + 1) * 28 + 2 * pj0);
        if (tid < 136) {
            const float* xb1 = x + (pairImg + 1) * 784;
            b0 = *(const float2*)(xb1 + (2 * pi1) * 28 + 2 * pj1);
            b1 = *(const float2*)(xb1 + (2 * pi1 + 1) * 28 + 2 * pj1);
        }
    };

    // phase 1: 392 tasks in 2 rounds; per-position math bitwise = R11.
    auto phase1 = [&]() {
        conv1_pos(a0, a1, w1t, sc1 + im0 * 1008, pi0, pj0);
        if (tid < 136) conv1_pos(b0, b1, w1t, sc1 + 1008, pi1, pj1);
    };

    // phase 2: 192 tasks = (img, oi, ojg, ocp, hf); per-task code = R11.
    auto phase2 = [&]() {
        if (tid < 192) {
            const int img = (tid >= 96) ? 1 : 0;
            int r = tid - img * 96;
            int oi = r >> 4, ojg = (r >> 3) & 1, ocp = (r >> 1) & 3, hf = r & 1;
            const float2* wbp = trig2 + ocp * 130;
            const float2* s1p = sc1 + img * 1008;
            float aY[3][2] = {{0.f,0.f},{0.f,0.f},{0.f,0.f}};
            float aX[3][2] = {{0.f,0.f},{0.f,0.f},{0.f,0.f}};
            #pragma unroll
            for (int ch = 0; ch < 4; ch++) {
                #pragma unroll
                for (int kk = 0; kk < 2; kk++) {
                    int ki = hf * 2 + kk;
                    int base = ch * 252 + (oi * 2 + ki) * 18 + ojg * 6;
                    float4 f0 = *(const float4*)(s1p + base);
                    float4 f1 = *(const float4*)(s1p + base + 2);
                    float4 f2 = *(const float4*)(s1p + base + 4);
                    float4 f3 = *(const float4*)(s1p + base + 6);
                    float ss[8] = {f0.x,f0.z,f1.x,f1.z,f2.x,f2.z,f3.x,f3.z};
                    float cc[8] = {f0.y,f0.w,f1.y,f1.w,f2.y,f2.w,f3.y,f3.w};
                    int e0 = ch * 16 + ki * 4;
                    #pragma unroll
                    for (int kj = 0; kj < 4; kj++) {
                        float4 wv = *(const float4*)(wbp + (e0 + kj) * 2); // (c0,s0,c1,s1)
                        #pragma unroll
                        for (int ojl = 0; ojl < 3; ojl++) {
                            float s = ss[ojl * 2 + kj], c = cc[ojl * 2 + kj];
                            aY[ojl][0] = fmaf(s, wv.x, fmaf(-c, wv.y, aY[ojl][0]));
                            aX[ojl][0] = fmaf(c, wv.x, fmaf( s, wv.y, aX[ojl][0]));
                            aY[ojl][1] = fmaf(s, wv.z, fmaf(-c, wv.w, aY[ojl][1]));
                            aX[ojl][1] = fmaf(c, wv.z, fmaf( s, wv.w, aX[ojl][1]));
                        }
                    }
                }
            }
            // even/odd lane pairs; img offset 96 is even -> pairs never
            // straddle images; __shfl_xor(,1) semantics identical to R11.
            #pragma unroll
            for (int ojl = 0; ojl < 3; ojl++) {
                float y0 = aY[ojl][0]; y0 += __shfl_xor(y0, 1);
                float y1 = aY[ojl][1]; y1 += __shfl_xor(y1, 1);
                float x0 = aX[ojl][0]; x0 += __shfl_xor(x0, 1);
                float x1 = aX[ojl][1]; x1 += __shfl_xor(x1, 1);
                float Y = hf ? y1 : y0;
                float X = hf ? x1 : x0;
                float inv = rsqrtf(fmaxf(fmaf(X, X, Y * Y), 1e-30f));
                int p = oi * 6 + ojg * 3 + ojl;
                sc2[img * 288 + p * 8 + ocp * 2 + hf] = make_float2(Y * inv, X * inv);
            }
        }
    };

    // phase 3: 640 tasks = (img, n, s32) in 3 rounds; per-output math = R11.
    auto phase3 = [&](size_t pairImg) {
        #pragma unroll
        for (int rr = 0; rr < 3; rr++) {
            int t = tid + (rr << 8);
            if (t < 640) {
                int img = (t >= 320) ? 1 : 0;
                int idx = t - img * 320;
                int n = idx >> 5, s = idx & 31;
                const float2* wn = fft + n * 288;
                const float2* s2p = sc2 + img * 288;
                float Y = 0.f, X = 0.f;
                #pragma unroll
                for (int i = 0; i < 9; i++) {
                    int k = i * 32 + s;
                    float2 sc = s2p[k];
                    float2 w = wn[k];
                    Y = fmaf(sc.x, w.x, fmaf(-sc.y, w.y, Y));
                    X = fmaf(sc.y, w.x, fmaf( sc.x, w.y, X));
                }
                #pragma unroll
                for (int off = 16; off > 0; off >>= 1) {
                    Y += __shfl_down(Y, off, 32);
                    X += __shfl_down(X, off, 32);
                }
                if (s == 0) {
                    out[(pairImg + img) * 10 + n] =
                        Y * rsqrtf(fmaxf(fmaf(X, X, Y * Y), 1e-30f));
                }
            }
        }
    };

    // ---- persistent 4-image schedule (2 pairs, pipelined), repeated REP x ----
    for (int i = tid; i < 260; i += 256)                 // trig2: once per block
        ((float4*)trig2)[i] = ((const float4*)(ws + W2_OFF))[i];
    loadPair(imgBase);
    __syncthreads();          // trig2 staged (once)
    for (int rep = 0; rep < REP; rep++) {
        phase1();
        __syncthreads();          // pair0 sc1 ready
        phase2();
        __syncthreads();          // pair0 sc2 ready; sc1 free
        loadPair(imgBase + 2);    // pair1 x-loads: latency hides under phase3
        phase3(imgBase);          // reads sc2 (pair0)
        phase1();                 // writes sc1 (pair1) -- disjoint from phase3
        __syncthreads();          // pair1 sc1 ready; sc2 free
        phase2();
        __syncthreads();          // pair1 sc2 ready
        phase3(imgBase + 2);
        if (rep + 1 < REP) loadPair(imgBase);  // reload pair0 for next rep
        // back-edge hazard: next rep's phase1 writes sc1, whose last readers
        // (this rep's second phase2) finished before the barrier above;
        // phase3 reads sc2 only -- disjoint. No extra barrier needed.
    }
}

extern "C" void kernel_launch(void* const* d_in, const int* in_sizes, int n_in,
                              void* d_out, int out_size, void* d_ws, size_t ws_size,
                              hipStream_t stream) {
    const float* x  = (const float*)d_in[0];
    const float* w1 = (const float*)d_in[1];
    const float* w2 = (const float*)d_in[2];
    const float* ff = (const float*)d_in[3];
    float* out = (float*)d_out;
    const int B = in_sizes[0] / 784;   // 4096

    float2* ws = (float2*)d_ws;
    precompute_trig<<<14, 256, 0, stream>>>(w1, w2, ff, ws);
    ringnn_kernel<<<B / 4, 256, 0, stream>>>(x, ws, out);   // 1024 = 4 blocks/CU
}

// Round 9
// 90.297 us; speedup vs baseline: 1.0607x; 1.0607x over previous
//
#include <hip/hip_runtime.h>
#include <math.h>

// Base = R15 (82.1us). R17 REP=2 diagnostic: warm marginal ringnn pass =
// 13.7us, matching the LDS-pipe cycle model -> LDS-PIPE-BOUND. R18/R19/R20:
// cut LDS-pipe instructions ~6x. R20 fixes R19's bug: P2 lane map had oi in
// 0..3 but conv2 has 6 output rows (oi 0..5) -> sc2 rows 4,5 stale garbage,
// absmax 0.45. Now P2 = 2 rounds x 4 images, lane = (imq:2, oi:3, ojg:1),
// active oi<6 (48/64 lanes).
//  * P2 weights: wave = ocp (readfirstlane -> SGPR), reads wave-uniform
//    GLOBAL -> s_load scalar broadcast; zero LDS traffic for trig2, no
//    staging, no staging barrier.
//  * each lane accumulates all 64 taps (no hf split, no P2 shfl).
//  * P3 reduce: DPP row_shr/bcast15 (pure VALU), zero ds_bpermute.
//  * LDS: 8*(786+292) f2 = 67.4KB -> 2 blocks/CU. 2 barriers per 8 images.
// Per-task FMA identical to R11; tap/reduce association differs (R12
// precedent: reassociation kept absmax 0.0; threshold 1.7e-2).
//
// d_ws trig layout (float2 = {cos,sin}):
//   [0,2880)    fft:   [n*288 + k]            (transposed ff_w trig)
//   [2880,3400) trig2: [ocp*130 + e*2 + (oc&1)], e = ch*16+ki*4+kj (pad 130)
//   [3400,3416) trig1: [oc*4 + e], e = a*2+c
#define FFT_OFF 0
#define W2_OFF 2880
#define W1_OFF 3400
#define S1 786   // per-image sc1 slice (f2): 4ch*196 + 2 pad
#define S2 292   // per-image sc2 slice (f2): 288 + 4 pad

__global__ void precompute_trig(const float* __restrict__ w1,
                                const float* __restrict__ w2,
                                const float* __restrict__ ff,
                                float2* __restrict__ ws) {
    int idx = blockIdx.x * blockDim.x + threadIdx.x;
    if (idx < 2880) {
        int k = idx / 10, n = idx % 10;
        float s, c; sincosf(ff[idx], &s, &c);
        ws[FFT_OFF + n * 288 + k] = make_float2(c, s);
    } else if (idx < 3392) {
        int i = idx - 2880;                  // i = oc*64 + e
        int oc = i >> 6, e = i & 63;
        float s, c; sincosf(w2[i], &s, &c);
        ws[W2_OFF + (oc >> 1) * 130 + e * 2 + (oc & 1)] = make_float2(c, s);
    } else if (idx < 3408) {
        int i = idx - 3392;
        float s, c; sincosf(w1[i], &s, &c);
        ws[W1_OFF + i] = make_float2(c, s);
    }
}

// One conv1 output position: 4 sincos + 4 oc x (16 fma + rsqrt).
// Math bitwise identical to R11; sc1 layout now ch*196 + pi*14 + pj.
__device__ __forceinline__ void conv1_pos(float2 r0, float2 r1,
                                          const float2* __restrict__ w1t,
                                          float2* __restrict__ sc1,
                                          int pi, int pj) {
    float sx[4], cx[4];
    __sincosf(r0.x, &sx[0], &cx[0]);
    __sincosf(r0.y, &sx[1], &cx[1]);
    __sincosf(r1.x, &sx[2], &cx[2]);
    __sincosf(r1.y, &sx[3], &cx[3]);
    #pragma unroll
    for (int oc = 0; oc < 4; oc++) {
        float4 wa = *(const float4*)(w1t + oc * 4);      // taps e0,e1 (uniform)
        float4 wb = *(const float4*)(w1t + oc * 4 + 2);  // taps e2,e3 (uniform)
        float Y = 0.f, X = 0.f;
        Y = fmaf(sx[0], wa.x, fmaf(-cx[0], wa.y, Y));
        X = fmaf(cx[0], wa.x, fmaf( sx[0], wa.y, X));
        Y = fmaf(sx[1], wa.z, fmaf(-cx[1], wa.w, Y));
        X = fmaf(cx[1], wa.z, fmaf( sx[1], wa.w, X));
        Y = fmaf(sx[2], wb.x, fmaf(-cx[2], wb.y, Y));
        X = fmaf(cx[2], wb.x, fmaf( sx[2], wb.y, X));
        Y = fmaf(sx[3], wb.z, fmaf(-cx[3], wb.w, Y));
        X = fmaf(cx[3], wb.z, fmaf( sx[3], wb.w, X));
        float inv = rsqrtf(fmaxf(fmaf(X, X, Y * Y), 1e-30f));
        sc1[oc * 196 + pi * 14 + pj] = make_float2(Y * inv, X * inv);
    }
}

// DPP add helper (pure VALU). CTRL is a hardware immediate -> template const.
template <int CTRL>
__device__ __forceinline__ float dpp_add(float v) {
    return v + __int_as_float(__builtin_amdgcn_mov_dpp(
                   __float_as_int(v), CTRL, 0xF, 0xF, true));
}
// 32-lane sum: row_shr 1/2/4/8 builds 16-lane row sums at lanes 15/31/47/63;
// row_bcast15 adds each row's lane15 into the next row -> lanes 31 and 63
// hold the sums of lanes 0..31 and 32..63 (bound_ctrl: OOB sources add 0).
__device__ __forceinline__ float reduce32(float v) {
    v = dpp_add<0x111>(v);  // row_shr:1
    v = dpp_add<0x112>(v);  // row_shr:2
    v = dpp_add<0x114>(v);  // row_shr:4
    v = dpp_add<0x118>(v);  // row_shr:8
    v = dpp_add<0x142>(v);  // row_bcast:15
    return v;
}

// 256 threads = 4 waves, 8 images/block, grid B/8 = 512.
// LDS: 8*(786+292) f2 = 67.4 KB -> 2 blocks/CU (8 waves/CU).
__global__ __launch_bounds__(256, 2) void ringnn_kernel(
    const float* __restrict__ x,
    const float2* __restrict__ ws,
    float* __restrict__ out)
{
    __shared__ __align__(16) float2 sc1[8 * S1];  // img*S1 + ch*196 + pi*14 + pj
    __shared__ __align__(16) float2 sc2[8 * S2];  // img*S2 + p*8 + oc
    const int tid = threadIdx.x;
    const int g = tid >> 5, s = tid & 31;          // 32-lane image-group (P1/P3)
    const size_t imgBase = (size_t)blockIdx.x * 8;
    const float2* __restrict__ fft = ws + FFT_OFF;
    const float2* __restrict__ w1t = ws + W1_OFF;

    // ---- phase 1: ring conv1 (2x2 stride 2); group g owns image g ----
    {
        const float* xp = x + (imgBase + g) * 784;
        float2* s1 = sc1 + g * S1;
        #pragma unroll
        for (int r = 0; r < 7; r++) {
            int pos = r * 32 + s;                  // 196 = 6*32 + 4
            if (pos < 196) {
                int pi = pos / 14, pj = pos % 14;
                float2 r0 = *(const float2*)(xp + (2 * pi) * 28 + 2 * pj);
                float2 r1 = *(const float2*)(xp + (2 * pi + 1) * 28 + 2 * pj);
                conv1_pos(r0, r1, w1t, s1, pi, pj);
            }
        }
    }
    __syncthreads();    // sc1 ready for all 8 images

    // ---- phase 2: ring conv2 (4x4 stride 2) ----
    // wave = ocp (SGPR); lane = (imq:2, oi:3, ojg:1), active oi<6;
    // 2 rounds x 4 images. Weights: wave-uniform GLOBAL -> scalar broadcast.
    {
        const int ocp = __builtin_amdgcn_readfirstlane(tid >> 6);
        const int l = tid & 63;
        const int imq = l >> 4;            // 0..3: image within round quartet
        const int oi  = (l >> 1) & 7;      // 0..7, active if < 6
        const int ojg = l & 1;
        const float2* __restrict__ wbp = ws + W2_OFF + ocp * 130;
        #pragma unroll
        for (int rr = 0; rr < 2; rr++) {
            const int im = rr * 4 + imq;
            if (oi < 6) {
                const float2* __restrict__ s1p = sc1 + im * S1;
                float aY[3][2] = {{0.f,0.f},{0.f,0.f},{0.f,0.f}};
                float aX[3][2] = {{0.f,0.f},{0.f,0.f},{0.f,0.f}};
                #pragma unroll
                for (int ch = 0; ch < 4; ch++) {
                    #pragma unroll
                    for (int ki = 0; ki < 4; ki++) {
                        int base = ch * 196 + (oi * 2 + ki) * 14 + ojg * 6;
                        float4 f0 = *(const float4*)(s1p + base);
                        float4 f1 = *(const float4*)(s1p + base + 2);
                        float4 f2 = *(const float4*)(s1p + base + 4);
                        float4 f3 = *(const float4*)(s1p + base + 6);
                        float ss[8] = {f0.x,f0.z,f1.x,f1.z,f2.x,f2.z,f3.x,f3.z};
                        float cc[8] = {f0.y,f0.w,f1.y,f1.w,f2.y,f2.w,f3.y,f3.w};
                        int e0 = ch * 16 + ki * 4;
                        #pragma unroll
                        for (int kj = 0; kj < 4; kj++) {
                            float4 wv = *(const float4*)(wbp + (e0 + kj) * 2); // scalar (c0,s0,c1,s1)
                            #pragma unroll
                            for (int ojl = 0; ojl < 3; ojl++) {
                                float sv = ss[ojl * 2 + kj], cv = cc[ojl * 2 + kj];
                                aY[ojl][0] = fmaf(sv, wv.x, fmaf(-cv, wv.y, aY[ojl][0]));
                                aX[ojl][0] = fmaf(cv, wv.x, fmaf( sv, wv.y, aX[ojl][0]));
                                aY[ojl][1] = fmaf(sv, wv.z, fmaf(-cv, wv.w, aY[ojl][1]));
                                aX[ojl][1] = fmaf(cv, wv.z, fmaf( sv, wv.w, aX[ojl][1]));
                            }
                        }
                    }
                }
                float2* s2p = sc2 + im * S2;
                #pragma unroll
                for (int ojl = 0; ojl < 3; ojl++) {
                    float Y0 = aY[ojl][0], X0 = aX[ojl][0];
                    float Y1 = aY[ojl][1], X1 = aX[ojl][1];
                    float i0 = rsqrtf(fmaxf(fmaf(X0, X0, Y0 * Y0), 1e-30f));
                    float i1 = rsqrtf(fmaxf(fmaf(X1, X1, Y1 * Y1), 1e-30f));
                    int p = oi * 6 + ojg * 3 + ojl;
                    // packed write: oc = 2*ocp, 2*ocp+1 (adjacent f2 slots)
                    *(float4*)(s2p + p * 8 + ocp * 2) =
                        make_float4(Y0 * i0, X0 * i0, Y1 * i1, X1 * i1);
                }
            }
        }
    }
    __syncthreads();    // sc2 ready for all 8 images

    // ---- phase 3: ring feed-forward; group g, round n -> output n ----
    {
        const float2* __restrict__ s2p = sc2 + g * S2;
        const size_t obase = (imgBase + g) * 10;
        #pragma unroll
        for (int n = 0; n < 10; n++) {
            const float2* __restrict__ wn = fft + n * 288;
            float Y = 0.f, X = 0.f;
            #pragma unroll
            for (int i = 0; i < 9; i++) {
                int k = i * 32 + s;
                float2 sc = s2p[k];
                float2 w = wn[k];
                Y = fmaf(sc.x, w.x, fmaf(-sc.y, w.y, Y));
                X = fmaf(sc.y, w.x, fmaf( sc.x, w.y, X));
            }
            Y = reduce32(Y);
            X = reduce32(X);
            if (s == 31) {
                out[obase + n] = Y * rsqrtf(fmaxf(fmaf(X, X, Y * Y), 1e-30f));
            }
        }
    }
}

extern "C" void kernel_launch(void* const* d_in, const int* in_sizes, int n_in,
                              void* d_out, int out_size, void* d_ws, size_t ws_size,
                              hipStream_t stream) {
    const float* x  = (const float*)d_in[0];
    const float* w1 = (const float*)d_in[1];
    const float* w2 = (const float*)d_in[2];
    const float* ff = (const float*)d_in[3];
    float* out = (float*)d_out;
    const int B = in_sizes[0] / 784;   // 4096

    float2* ws = (float2*)d_ws;
    precompute_trig<<<14, 256, 0, stream>>>(w1, w2, ff, ws);
    ringnn_kernel<<<B / 8, 256, 0, stream>>>(x, ws, out);   // 512 blocks
}

// Round 10
// 80.695 us; speedup vs baseline: 1.1869x; 1.1190x over previous
//
#include <hip/hip_runtime.h>
#include <math.h>

// Base = R15 (82.1us, absmax 0.0 -- best verified). R21 = R15 with two
// strictly-positive micro-changes, everything else bit-identical:
//  (1) P3 reduce: __shfl_down tree (10 ds_bpermute+add per task) -> DPP
//      row_shr/bcast15 reduce32 (5 pure-VALU adds). Halves reduce instrs
//      AND removes its LDS-pipe traffic. Numerically validated in R20
//      (absmax 0.0). Writer lane changes s==0 -> s==31 (sum lands there).
//  (2) precompute_trig: sincosf -> __sincosf (same family P1 uses; bf16
//      output + 1.7e-2 threshold; R11..R20 precedent). ~2x faster dispatch.
// R20 post-mortem: LDS-cut restructure regressed (90.3) -- traded LDS instrs
// for VALU issue waste (48/64 lanes x 2 rounds) + halved blocks/CU. Kernel
// is VALU+LDS dependency-serialized, not single-pipe-bound; only total-work
// cuts or overlap improvements pay. Hence: keep R15 schedule, shave both.
//
// d_ws trig layout (float2 = {cos,sin}):
//   [0,2880)    fft:   [n*288 + k]            (transposed ff_w trig)
//   [2880,3400) trig2: [ocp*130 + e*2 + (oc&1)], e = ch*16+ki*4+kj (pad 130)
//   [3400,3416) trig1: [oc*4 + e], e = a*2+c
#define FFT_OFF 0
#define W2_OFF 2880
#define W1_OFF 3400

__global__ void precompute_trig(const float* __restrict__ w1,
                                const float* __restrict__ w2,
                                const float* __restrict__ ff,
                                float2* __restrict__ ws) {
    int idx = blockIdx.x * blockDim.x + threadIdx.x;
    if (idx < 2880) {
        int k = idx / 10, n = idx % 10;
        float s, c; __sincosf(ff[idx], &s, &c);
        ws[FFT_OFF + n * 288 + k] = make_float2(c, s);
    } else if (idx < 3392) {
        int i = idx - 2880;                  // i = oc*64 + e
        int oc = i >> 6, e = i & 63;
        float s, c; __sincosf(w2[i], &s, &c);
        ws[W2_OFF + (oc >> 1) * 130 + e * 2 + (oc & 1)] = make_float2(c, s);
    } else if (idx < 3408) {
        int i = idx - 3392;
        float s, c; __sincosf(w1[i], &s, &c);
        ws[W1_OFF + i] = make_float2(c, s);
    }
}

// One conv1 output position: 4 sincos + 4 oc x (16 fma + rsqrt).
// Bitwise identical to R11's per-position phase-1 body.
__device__ __forceinline__ void conv1_pos(float2 r0, float2 r1,
                                          const float2* __restrict__ w1t,
                                          float2* __restrict__ sc1,
                                          int pi, int pj) {
    float sx[4], cx[4];
    __sincosf(r0.x, &sx[0], &cx[0]);
    __sincosf(r0.y, &sx[1], &cx[1]);
    __sincosf(r1.x, &sx[2], &cx[2]);
    __sincosf(r1.y, &sx[3], &cx[3]);
    #pragma unroll
    for (int oc = 0; oc < 4; oc++) {
        float4 wa = *(const float4*)(w1t + oc * 4);      // taps e0,e1 (uniform)
        float4 wb = *(const float4*)(w1t + oc * 4 + 2);  // taps e2,e3 (uniform)
        float Y = 0.f, X = 0.f;
        Y = fmaf(sx[0], wa.x, fmaf(-cx[0], wa.y, Y));
        X = fmaf(cx[0], wa.x, fmaf( sx[0], wa.y, X));
        Y = fmaf(sx[1], wa.z, fmaf(-cx[1], wa.w, Y));
        X = fmaf(cx[1], wa.z, fmaf( sx[1], wa.w, X));
        Y = fmaf(sx[2], wb.x, fmaf(-cx[2], wb.y, Y));
        X = fmaf(cx[2], wb.x, fmaf( sx[2], wb.y, X));
        Y = fmaf(sx[3], wb.z, fmaf(-cx[3], wb.w, Y));
        X = fmaf(cx[3], wb.z, fmaf( sx[3], wb.w, X));
        float inv = rsqrtf(fmaxf(fmaf(X, X, Y * Y), 1e-30f));
        sc1[oc * 252 + pi * 18 + pj] = make_float2(Y * inv, X * inv);
    }
}

// DPP add helper (pure VALU, zero LDS-pipe traffic). CTRL = HW immediate.
template <int CTRL>
__device__ __forceinline__ float dpp_add(float v) {
    return v + __int_as_float(__builtin_amdgcn_mov_dpp(
                   __float_as_int(v), CTRL, 0xF, 0xF, true));
}
// 32-lane sum (validated absmax 0.0 in R20): row_shr 1/2/4/8 builds 16-lane
// row sums at lanes 15/31/47/63; row_bcast15 adds each even row's lane15
// into the next row -> lanes 31 and 63 hold their 32-half's total.
__device__ __forceinline__ float reduce32(float v) {
    v = dpp_add<0x111>(v);  // row_shr:1
    v = dpp_add<0x112>(v);  // row_shr:2
    v = dpp_add<0x114>(v);  // row_shr:4
    v = dpp_add<0x118>(v);  // row_shr:8
    v = dpp_add<0x142>(v);  // row_bcast:15
    return v;
}

// 256 threads = 4 waves, 4 images/block (2 pairs), grid B/4 = 1024.
__global__ __launch_bounds__(256, 4) void ringnn_kernel(
    const float* __restrict__ x,
    const float2* __restrict__ ws,
    float* __restrict__ out)
{
    __shared__ __align__(16) float2 trig2[520];
    __shared__ __align__(16) float2 sc1[2 * 1008]; // img*1008 + ch*252 + row*18 + col
    __shared__ __align__(16) float2 sc2[2 * 288];  // img*288 + p*8 + oc
    const int tid = threadIdx.x;
    const float2* __restrict__ fft = ws + FFT_OFF;
    const float2* __restrict__ w1t = ws + W1_OFF;
    const size_t imgBase = (size_t)blockIdx.x * 4;

    // ---- per-thread position maps (constant across pairs) ----
    const int im0 = (tid >= 196) ? 1 : 0;
    const int p0  = tid - im0 * 196;
    const int pi0 = p0 / 14, pj0 = p0 % 14;
    const int pr1 = tid + 60;                   // img1 pos for round 1 (tid<136)
    const int pi1 = pr1 / 14, pj1 = pr1 % 14;

    float2 a0, a1, b0 = make_float2(0.f, 0.f), b1 = make_float2(0.f, 0.f);

    auto loadPair = [&](size_t pairImg) {
        const float* xb0 = x + (pairImg + im0) * 784;
        a0 = *(const float2*)(xb0 + (2 * pi0) * 28 + 2 * pj0);
        a1 = *(const float2*)(xb0 + (2 * pi0 + 1) * 28 + 2 * pj0);
        if (tid < 136) {
            const float* xb1 = x + (pairImg + 1) * 784;
            b0 = *(const float2*)(xb1 + (2 * pi1) * 28 + 2 * pj1);
            b1 = *(const float2*)(xb1 + (2 * pi1 + 1) * 28 + 2 * pj1);
        }
    };

    // phase 1: 392 tasks in 2 rounds; per-position math bitwise = R11.
    auto phase1 = [&]() {
        conv1_pos(a0, a1, w1t, sc1 + im0 * 1008, pi0, pj0);
        if (tid < 136) conv1_pos(b0, b1, w1t, sc1 + 1008, pi1, pj1);
    };

    // phase 2: 192 tasks = (img, oi, ojg, ocp, hf); per-task code = R11.
    auto phase2 = [&]() {
        if (tid < 192) {
            const int img = (tid >= 96) ? 1 : 0;
            int r = tid - img * 96;
            int oi = r >> 4, ojg = (r >> 3) & 1, ocp = (r >> 1) & 3, hf = r & 1;
            const float2* wbp = trig2 + ocp * 130;
            const float2* s1p = sc1 + img * 1008;
            float aY[3][2] = {{0.f,0.f},{0.f,0.f},{0.f,0.f}};
            float aX[3][2] = {{0.f,0.f},{0.f,0.f},{0.f,0.f}};
            #pragma unroll
            for (int ch = 0; ch < 4; ch++) {
                #pragma unroll
                for (int kk = 0; kk < 2; kk++) {
                    int ki = hf * 2 + kk;
                    int base = ch * 252 + (oi * 2 + ki) * 18 + ojg * 6;
                    float4 f0 = *(const float4*)(s1p + base);
                    float4 f1 = *(const float4*)(s1p + base + 2);
                    float4 f2 = *(const float4*)(s1p + base + 4);
                    float4 f3 = *(const float4*)(s1p + base + 6);
                    float ss[8] = {f0.x,f0.z,f1.x,f1.z,f2.x,f2.z,f3.x,f3.z};
                    float cc[8] = {f0.y,f0.w,f1.y,f1.w,f2.y,f2.w,f3.y,f3.w};
                    int e0 = ch * 16 + ki * 4;
                    #pragma unroll
                    for (int kj = 0; kj < 4; kj++) {
                        float4 wv = *(const float4*)(wbp + (e0 + kj) * 2); // (c0,s0,c1,s1)
                        #pragma unroll
                        for (int ojl = 0; ojl < 3; ojl++) {
                            float s = ss[ojl * 2 + kj], c = cc[ojl * 2 + kj];
                            aY[ojl][0] = fmaf(s, wv.x, fmaf(-c, wv.y, aY[ojl][0]));
                            aX[ojl][0] = fmaf(c, wv.x, fmaf( s, wv.y, aX[ojl][0]));
                            aY[ojl][1] = fmaf(s, wv.z, fmaf(-c, wv.w, aY[ojl][1]));
                            aX[ojl][1] = fmaf(c, wv.z, fmaf( s, wv.w, aX[ojl][1]));
                        }
                    }
                }
            }
            // even/odd lane pairs; img offset 96 is even -> pairs never
            // straddle images; __shfl_xor(,1) semantics identical to R11.
            #pragma unroll
            for (int ojl = 0; ojl < 3; ojl++) {
                float y0 = aY[ojl][0]; y0 += __shfl_xor(y0, 1);
                float y1 = aY[ojl][1]; y1 += __shfl_xor(y1, 1);
                float x0 = aX[ojl][0]; x0 += __shfl_xor(x0, 1);
                float x1 = aX[ojl][1]; x1 += __shfl_xor(x1, 1);
                float Y = hf ? y1 : y0;
                float X = hf ? x1 : x0;
                float inv = rsqrtf(fmaxf(fmaf(X, X, Y * Y), 1e-30f));
                int p = oi * 6 + ojg * 3 + ojl;
                sc2[img * 288 + p * 8 + ocp * 2 + hf] = make_float2(Y * inv, X * inv);
            }
        }
    };

    // phase 3: 640 tasks = (img, n, s32) in 3 rounds; DPP reduce (R21).
    auto phase3 = [&](size_t pairImg) {
        #pragma unroll
        for (int rr = 0; rr < 3; rr++) {
            int t = tid + (rr << 8);
            if (t < 640) {
                int img = (t >= 320) ? 1 : 0;
                int idx = t - img * 320;
                int n = idx >> 5, s = idx & 31;
                const float2* wn = fft + n * 288;
                const float2* s2p = sc2 + img * 288;
                float Y = 0.f, X = 0.f;
                #pragma unroll
                for (int i = 0; i < 9; i++) {
                    int k = i * 32 + s;
                    float2 sc = s2p[k];
                    float2 w = wn[k];
                    Y = fmaf(sc.x, w.x, fmaf(-sc.y, w.y, Y));
                    X = fmaf(sc.y, w.x, fmaf( sc.x, w.y, X));
                }
                Y = reduce32(Y);
                X = reduce32(X);
                if (s == 31) {
                    out[(pairImg + img) * 10 + n] =
                        Y * rsqrtf(fmaxf(fmaf(X, X, Y * Y), 1e-30f));
                }
            }
        }
    };

    // ---- persistent 4-image schedule (2 pairs, software-pipelined) ----
    loadPair(imgBase);
    for (int i = tid; i < 260; i += 256)                 // trig2: once per block
        ((float4*)trig2)[i] = ((const float4*)(ws + W2_OFF))[i];
    phase1();
    __syncthreads();          // trig2 staged + pair0 sc1 ready
    phase2();
    __syncthreads();          // pair0 sc2 ready; sc1 free
    loadPair(imgBase + 2);    // pair1 x-loads: latency hides under phase3
    phase3(imgBase);          // reads sc2 (pair0)
    phase1();                 // writes sc1 (pair1) -- disjoint from phase3
    __syncthreads();          // pair1 sc1 ready; sc2 free
    phase2();
    __syncthreads();          // pair1 sc2 ready
    phase3(imgBase + 2);
}

extern "C" void kernel_launch(void* const* d_in, const int* in_sizes, int n_in,
                              void* d_out, int out_size, void* d_ws, size_t ws_size,
                              hipStream_t stream) {
    const float* x  = (const float*)d_in[0];
    const float* w1 = (const float*)d_in[1];
    const float* w2 = (const float*)d_in[2];
    const float* ff = (const float*)d_in[3];
    float* out = (float*)d_out;
    const int B = in_sizes[0] / 784;   // 4096

    float2* ws = (float2*)d_ws;
    precompute_trig<<<14, 256, 0, stream>>>(w1, w2, ff, ws);
    ringnn_kernel<<<B / 4, 256, 0, stream>>>(x, ws, out);   // 1024 = 4 blocks/CU
}